// Round 10
// baseline (178.763 us; speedup 1.0000x reference)
//
#include <hip/hip_runtime.h>
#include <math.h>

// ---------------------------------------------------------------------------
// DMoN pooling, edge-list formulation (dense adj never materialized).
//   0. zero_init: deg/wdeg/cnt/ctr
//   1. count_convert: per-edge cnt/deg/wdeg atomics (rank = returned count!)
//      + x->bf16 + W1/W2 -> transposed bf16 hi/lo (independent blocks)
//   2. scan_dis: rowptr scan + dis = rsqrt(deg+1)
//   3. scatter: p = rowptr[dst] + rank[e]  (NO atomics)
//   4. layer 1: (axhi,axlo) = split(aggregate(x_bf)) ; h_bf = relu(ax@W1+b1)
//   5. layer 2: (ahhi,ahlo) = split(aggregate(h_bf)) ; h2 = relu(ah@W2+b2)
//      aggregates: wave-per-node, shuffle cross-slot reduce (no LDS)
//   6. pool: s = softmax(h2@Wp+bp) -> d_out ; partials cs/ca/wsum
//   7. edge_reduce: tr = SUM_e w*dot(s_src,s_dst); last block runs the
//      PARALLEL finalize (threadfence+ctr protocol) and emits 3 scalars
// ---------------------------------------------------------------------------

#define ER_BLOCKS 512

typedef unsigned short u16;
typedef __attribute__((ext_vector_type(8))) short short8v;
typedef __attribute__((ext_vector_type(4))) float float4v;
typedef __attribute__((ext_vector_type(4))) unsigned short ushort4v;
typedef __attribute__((ext_vector_type(8))) unsigned short ushort8v;

__device__ __forceinline__ u16 f2bf_rne(float x) {
  unsigned u = __float_as_uint(x);
  u = (u + 0x7fffu + ((u >> 16) & 1u)) >> 16;
  return (u16)u;
}
__device__ __forceinline__ float bf2f(u16 h) {
  return __uint_as_float(((unsigned)h) << 16);
}

// edge_index declared int64 in the reference, but JAX without x64 keeps int32.
__device__ __forceinline__ bool ei_is_i64(const int* __restrict__ ei) {
  return ((ei[1] | ei[3] | ei[5] | ei[7]) == 0);
}
__device__ __forceinline__ int ld_idx(const int* __restrict__ ei, int pos, bool i64) {
  return i64 ? ei[2 * pos] : ei[pos];
}

__global__ __launch_bounds__(256) void zero_init(int4* __restrict__ p, int n4) {
  int i = blockIdx.x * 256 + threadIdx.x;
  if (i < n4) p[i] = make_int4(0, 0, 0, 0);
}

// Blocks [0,eb): edge counting (rank from atomic return). Blocks [eb,..):
// x->bf16 and W1/W2 -> transposed bf16 hi/lo conversion cascade.
__global__ __launch_bounds__(256) void count_convert(const int* __restrict__ ei,
                                                     const float* __restrict__ ew,
                                                     int* __restrict__ cnt,
                                                     float* __restrict__ deg,
                                                     float* __restrict__ wdeg,
                                                     int* __restrict__ rank, int E,
                                                     const float* __restrict__ x,
                                                     u16* __restrict__ xbf, int nx4,
                                                     const float* __restrict__ W1,
                                                     u16* __restrict__ w1hi, u16* __restrict__ w1lo,
                                                     const float* __restrict__ W2,
                                                     u16* __restrict__ w2hi, u16* __restrict__ w2lo) {
  const int T1 = 256 * 128, T2 = 256 * 256;
  int eb = (E + 255) >> 8;
  int b = blockIdx.x;
  if (b < eb) {
    int e = b * 256 + threadIdx.x;
    if (e >= E) return;
    bool i64 = ei_is_i64(ei);
    int s = ld_idx(ei, e, i64);
    int d = ld_idx(ei, E + e, i64);
    float we = ew[e];
    rank[e] = atomicAdd(&cnt[d], 1);  // rank within dst row
    atomicAdd(&deg[d], we);
    atomicAdd(&wdeg[s], we);
    return;
  }
  int idx = (b - eb) * 256 + threadIdx.x;
  if (idx < nx4) {
    float4 v = reinterpret_cast<const float4*>(x)[idx];
    ushort4v o = {f2bf_rne(v.x), f2bf_rne(v.y), f2bf_rne(v.z), f2bf_rne(v.w)};
    reinterpret_cast<ushort4v*>(xbf)[idx] = o;
    return;
  }
  idx -= nx4;
  if (idx < T1) {
    int n = idx >> 7, k = idx & 127;
    float v = W1[k * 256 + n];
    u16 h = f2bf_rne(v);
    w1hi[idx] = h;
    w1lo[idx] = f2bf_rne(v - bf2f(h));
    return;
  }
  idx -= T1;
  if (idx < T2) {
    int n = idx >> 8, k = idx & 255;
    float v = W2[k * 256 + n];
    u16 h = f2bf_rne(v);
    w2hi[idx] = h;
    w2lo[idx] = f2bf_rne(v - bf2f(h));
  }
}

// Single block: chunked scan cnt->rowptr, plus dis = rsqrt(deg+1).
__global__ __launch_bounds__(1024) void scan_dis(const int* __restrict__ cnt,
                                                 int* __restrict__ rowptr,
                                                 const float* __restrict__ deg,
                                                 float* __restrict__ dis, int n) {
  __shared__ int sums[1024];
  int tid = threadIdx.x;
  for (int i = tid; i < n; i += 1024) dis[i] = 1.0f / sqrtf(deg[i] + 1.0f);
  int CH = (n + 1023) >> 10;
  int beg = tid * CH, end = min(beg + CH, n);
  int s = 0;
  for (int i = beg; i < end; ++i) s += cnt[i];
  sums[tid] = s;
  __syncthreads();
  for (int off = 1; off < 1024; off <<= 1) {
    int v = (tid >= off) ? sums[tid - off] : 0;
    __syncthreads();
    sums[tid] += v;
    __syncthreads();
  }
  int run = (tid == 0) ? 0 : sums[tid - 1];
  for (int i = beg; i < end; ++i) { rowptr[i] = run; run += cnt[i]; }
  if (tid == 1023) rowptr[n] = run;
}

// Atomic-free scatter using precomputed rank.
__global__ __launch_bounds__(256) void scatter_edges(const int* __restrict__ ei,
                                                     const float* __restrict__ ew,
                                                     const int* __restrict__ rowptr,
                                                     const int* __restrict__ rank,
                                                     const float* __restrict__ dis,
                                                     int* __restrict__ col,
                                                     float* __restrict__ coef, int E) {
  int e = blockIdx.x * 256 + threadIdx.x;
  if (e >= E) return;
  bool i64 = ei_is_i64(ei);
  int s = ld_idx(ei, e, i64);
  int d = ld_idx(ei, E + e, i64);
  int p = rowptr[d] + rank[e];
  col[p] = s;
  coef[p] = dis[s] * ew[e] * dis[d];
}

// Normalized aggregation: wave-per-node, bf16 gather (16B/lane), fp32 accum,
// cross-slot reduce via shuffles (no LDS, no syncthreads), hi/lo output.
template <int CH>
__global__ __launch_bounds__(256) void aggregate_pre(const u16* __restrict__ src,
                                                     const int* __restrict__ rowptr,
                                                     const int* __restrict__ col,
                                                     const float* __restrict__ coef,
                                                     const float* __restrict__ deg,
                                                     u16* __restrict__ ohi,
                                                     u16* __restrict__ olo, int N) {
  constexpr int Q = CH / 8;   // ushort8 chunks per row: 16 (128ch) / 32 (256ch)
  constexpr int NS = 64 / Q;  // edge slots per wave: 4 / 2
  int wave = threadIdx.x >> 6;
  int lane = threadIdx.x & 63;
  int i = blockIdx.x * 4 + wave;
  if (i >= N) return;
  int q = lane % Q, slot = lane / Q;
  int e0 = rowptr[i], e1 = rowptr[i + 1];
  float a[8] = {};
  for (int p = e0 + slot; p < e1; p += NS) {
    int c = col[p];
    float w = coef[p];
    ushort8v v = *reinterpret_cast<const ushort8v*>(&src[(size_t)c * CH + q * 8]);
#pragma unroll
    for (int j = 0; j < 8; ++j) a[j] += w * bf2f(v[j]);
  }
  if constexpr (NS == 4) {
#pragma unroll
    for (int j = 0; j < 8; ++j) a[j] += __shfl_xor(a[j], 16);
  }
#pragma unroll
  for (int j = 0; j < 8; ++j) a[j] += __shfl_xor(a[j], 32);
  if (slot == 0) {
    float w0 = 1.0f / (deg[i] + 1.0f);  // self-loop term
    ushort8v xv = *reinterpret_cast<const ushort8v*>(&src[(size_t)i * CH + q * 8]);
    ushort8v hv, lv;
#pragma unroll
    for (int j = 0; j < 8; ++j) {
      a[j] += w0 * bf2f(xv[j]);
      u16 h = f2bf_rne(a[j]);
      hv[j] = h;
      lv[j] = f2bf_rne(a[j] - bf2f(h));
    }
    *reinterpret_cast<ushort8v*>(&ohi[(size_t)i * CH + q * 8]) = hv;
    *reinterpret_cast<ushort8v*>(&olo[(size_t)i * CH + q * 8]) = lv;
  }
}

// C[M,256] = relu(A@B + bias) via 3-term bf16 MFMA (A=Ahi+Alo, B=Bhi+Blo).
__global__ __launch_bounds__(256) void gemm_mfma(const u16* __restrict__ Ahi,
                                                 const u16* __restrict__ Alo,
                                                 const u16* __restrict__ Wthi,
                                                 const u16* __restrict__ Wtlo,
                                                 const float* __restrict__ bias,
                                                 float* __restrict__ C,
                                                 u16* __restrict__ Cbf,
                                                 int M, int K, int outbf) {
  __shared__ u16 As_hi[64][40], As_lo[64][40];
  __shared__ u16 Bs_hi[64][40], Bs_lo[64][40];
  int tid = threadIdx.x;
  int w = tid >> 6, l = tid & 63;
  int wm = w >> 1, wn = w & 1;
  int row0 = blockIdx.x * 64, col0 = blockIdx.y * 64;
  int srow = tid >> 2, sc = (tid & 3) * 8;
  int fr = l & 15, kg = (l >> 4) * 8;

  float4v acc[2][2];
#pragma unroll
  for (int i = 0; i < 2; ++i)
#pragma unroll
    for (int j = 0; j < 2; ++j) acc[i][j] = (float4v){0.f, 0.f, 0.f, 0.f};

  for (int k0 = 0; k0 < K; k0 += 32) {
    {
      int gr = row0 + srow;
      uint4 zero = make_uint4(0, 0, 0, 0);
      uint4 vh = zero, vl = zero;
      if (gr < M) {
        vh = *reinterpret_cast<const uint4*>(&Ahi[(size_t)gr * K + k0 + sc]);
        vl = *reinterpret_cast<const uint4*>(&Alo[(size_t)gr * K + k0 + sc]);
      }
      *reinterpret_cast<uint4*>(&As_hi[srow][sc]) = vh;
      *reinterpret_cast<uint4*>(&As_lo[srow][sc]) = vl;
      int bn = col0 + srow;
      uint4 bh = *reinterpret_cast<const uint4*>(&Wthi[(size_t)bn * K + k0 + sc]);
      uint4 bl = *reinterpret_cast<const uint4*>(&Wtlo[(size_t)bn * K + k0 + sc]);
      *reinterpret_cast<uint4*>(&Bs_hi[srow][sc]) = bh;
      *reinterpret_cast<uint4*>(&Bs_lo[srow][sc]) = bl;
    }
    __syncthreads();
    short8v ah[2], al[2], bh[2], bl[2];
#pragma unroll
    for (int i = 0; i < 2; ++i) {
      int r = wm * 32 + i * 16 + fr;
      ah[i] = *reinterpret_cast<const short8v*>(&As_hi[r][kg]);
      al[i] = *reinterpret_cast<const short8v*>(&As_lo[r][kg]);
    }
#pragma unroll
    for (int j = 0; j < 2; ++j) {
      int n = wn * 32 + j * 16 + fr;
      bh[j] = *reinterpret_cast<const short8v*>(&Bs_hi[n][kg]);
      bl[j] = *reinterpret_cast<const short8v*>(&Bs_lo[n][kg]);
    }
#pragma unroll
    for (int i = 0; i < 2; ++i)
#pragma unroll
      for (int j = 0; j < 2; ++j) {
        acc[i][j] = __builtin_amdgcn_mfma_f32_16x16x32_bf16(ah[i], bh[j], acc[i][j], 0, 0, 0);
        acc[i][j] = __builtin_amdgcn_mfma_f32_16x16x32_bf16(al[i], bh[j], acc[i][j], 0, 0, 0);
        acc[i][j] = __builtin_amdgcn_mfma_f32_16x16x32_bf16(ah[i], bl[j], acc[i][j], 0, 0, 0);
      }
    __syncthreads();
  }
#pragma unroll
  for (int j = 0; j < 2; ++j) {
    int gc = col0 + wn * 32 + j * 16 + fr;
    float bj = bias[gc];
#pragma unroll
    for (int i = 0; i < 2; ++i) {
#pragma unroll
      for (int r = 0; r < 4; ++r) {
        int gr = row0 + wm * 32 + i * 16 + (l >> 4) * 4 + r;
        if (gr < M) {
          float v = fmaxf(acc[i][j][r] + bj, 0.0f);
          if (outbf) Cbf[(size_t)gr * 256 + gc] = f2bf_rne(v);
          else       C[(size_t)gr * 256 + gc] = v;
        }
      }
    }
  }
}

// Pooling + softmax; per-block partials: [0..15]=cs, [16..31]=ca, [32]=wsum.
__global__ __launch_bounds__(256) void pool_kernel(const float* __restrict__ h,
                                                   const float* __restrict__ Wp,
                                                   const float* __restrict__ bp,
                                                   const float* __restrict__ wdeg,
                                                   float* __restrict__ s_out,
                                                   float* __restrict__ pp, int N) {
  __shared__ float Wps[256 * 16];
  __shared__ float loc[33];
  int tid = threadIdx.x;
  for (int idx = tid; idx < 4096; idx += 256) Wps[idx] = Wp[idx];
  if (tid < 33) loc[tid] = 0.f;
  __syncthreads();
  int lane = tid & 63;
  int wave = tid >> 6;
  int k = lane & 15, g = lane >> 4;
  int node = blockIdx.x * 16 + wave * 4 + g;
  float acc = 0.f, wd = 0.f;
  if (node < N) {
    wd = wdeg[node];
    const float4* hrow = reinterpret_cast<const float4*>(h + (size_t)node * 256);
#pragma unroll 8
    for (int c4 = 0; c4 < 64; ++c4) {
      float4 hv = hrow[c4];
      int cb = c4 * 4;
      acc += hv.x * Wps[(cb + 0) * 16 + k];
      acc += hv.y * Wps[(cb + 1) * 16 + k];
      acc += hv.z * Wps[(cb + 2) * 16 + k];
      acc += hv.w * Wps[(cb + 3) * 16 + k];
    }
    acc += bp[k];
  }
  float mx = acc;
#pragma unroll
  for (int off = 1; off < 16; off <<= 1) mx = fmaxf(mx, __shfl_xor(mx, off));
  float ex = (node < N) ? expf(acc - mx) : 0.f;
  float sm = ex;
#pragma unroll
  for (int off = 1; off < 16; off <<= 1) sm += __shfl_xor(sm, off);
  float sval = (node < N) ? ex / sm : 0.f;
  if (node < N) s_out[(size_t)node * 16 + k] = sval;
  float v = sval;
  float v2 = wd * sval;
  float v3 = (k == 0) ? wd : 0.f;
  v += __shfl_xor(v, 16);  v += __shfl_xor(v, 32);
  v2 += __shfl_xor(v2, 16); v2 += __shfl_xor(v2, 32);
  v3 += __shfl_xor(v3, 16); v3 += __shfl_xor(v3, 32);
  if (lane < 16) {
    atomicAdd(&loc[lane], v);
    atomicAdd(&loc[16 + lane], v2);
  }
  if (lane == 0) atomicAdd(&loc[32], v3);
  __syncthreads();
  if (tid < 33) pp[(size_t)blockIdx.x * 33 + tid] = loc[tid];
}

// tr = SUM_e w*dot(s_src,s_dst); 4 lanes/edge. Last block (ctr protocol)
// runs the PARALLEL finalize and emits the 3 scalars.
__global__ __launch_bounds__(256) void edge_reduce(const int* __restrict__ ei,
                                                   const float* __restrict__ ew,
                                                   const float* __restrict__ s,
                                                   float* __restrict__ part,
                                                   const float* __restrict__ pp, int pb,
                                                   int* __restrict__ ctr,
                                                   float* __restrict__ out,
                                                   int N, int s_elems, int E) {
  int tid = threadIdx.x;
  bool i64 = ei_is_i64(ei);
  int le = tid >> 2, sub = tid & 3;
  int epi = gridDim.x * 64;
  float acc = 0.f;
  for (int e = blockIdx.x * 64 + le; e < E; e += epi) {
    int a = ld_idx(ei, e, i64);
    int b = ld_idx(ei, E + e, i64);
    float w = ew[e];
    float4 av = *reinterpret_cast<const float4*>(s + (size_t)a * 16 + sub * 4);
    float4 bv = *reinterpret_cast<const float4*>(s + (size_t)b * 16 + sub * 4);
    float d = av.x * bv.x + av.y * bv.y + av.z * bv.z + av.w * bv.w;
    d += __shfl_xor(d, 1);
    d += __shfl_xor(d, 2);
    acc += w * d;  // 4 lane-copies/group; xor-4+ reduce counts each group once
  }
#pragma unroll
  for (int off = 4; off < 64; off <<= 1) acc += __shfl_xor(acc, off);
  __shared__ float loc;
  if (tid == 0) loc = 0.f;
  __syncthreads();
  if ((tid & 63) == 0) atomicAdd(&loc, acc);
  __syncthreads();
  if (tid == 0) part[blockIdx.x] = loc;

  // last-block parallel finalize
  __shared__ bool amLast;
  __threadfence();
  if (tid == 0) amLast = (atomicAdd(ctr, 1) == (int)gridDim.x - 1);
  __syncthreads();
  if (!amLast) return;

  __shared__ float cred[256];
  __shared__ float vals[32];
  __shared__ float scal[2];
  float a = 0.f;
  for (int b = tid; b < (int)gridDim.x; b += 256) a += part[b];
  float wv = 0.f;
  for (int b = tid; b < pb; b += 256) wv += pp[(size_t)b * 33 + 32];
#pragma unroll
  for (int off = 1; off < 64; off <<= 1) {
    a += __shfl_xor(a, off);
    wv += __shfl_xor(wv, off);
  }
  if (tid == 0) { scal[0] = 0.f; scal[1] = 0.f; }
  __syncthreads();
  if ((tid & 63) == 0) {
    atomicAdd(&scal[0], a);
    atomicAdd(&scal[1], wv);
  }
  {
    int k = tid & 31, sl = tid >> 5;
    float c = 0.f;
    for (int b = sl; b < pb; b += 8) c += pp[(size_t)b * 33 + k];
    cred[tid] = c;
  }
  __syncthreads();
  if (tid < 32) {
    float c = cred[tid];
#pragma unroll
    for (int sl = 1; sl < 8; ++sl) c += cred[sl * 32 + tid];
    vals[tid] = c;
  }
  __syncthreads();
  if (tid == 0) {
    float tr = scal[0], m2 = scal[1];
    float ca2 = 0.f, cs2 = 0.f;
    for (int k = 0; k < 16; ++k) {
      cs2 += vals[k] * vals[k];
      ca2 += vals[16 + k] * vals[16 + k];
    }
    float sp = -(tr - ca2 / m2) / m2;
    float cl = sqrtf(cs2) / (float)N * 4.0f - 1.0f;
    out[s_elems + 0] = 100.f * (sp + cl);
    out[s_elems + 1] = 100.f * sp;
    out[s_elems + 2] = 100.f * cl;
  }
}

extern "C" void kernel_launch(void* const* d_in, const int* in_sizes, int n_in,
                              void* d_out, int out_size, void* d_ws, size_t ws_size,
                              hipStream_t stream) {
  const float* x  = (const float*)d_in[0];
  const int*   ei = (const int*)d_in[1];
  const float* ew = (const float*)d_in[2];
  const float* W1 = (const float*)d_in[3];
  const float* b1 = (const float*)d_in[4];
  const float* W2 = (const float*)d_in[5];
  const float* b2 = (const float*)d_in[6];
  const float* Wp = (const float*)d_in[7];
  const float* bp = (const float*)d_in[8];
  float* out = (float*)d_out;

  const int IN_C = 128, HID = 256;
  const int N = in_sizes[0] / IN_C;   // 10000
  const int E = in_sizes[2];          // 160000
  const int pool_blocks = (N + 15) / 16;

  char* p = (char*)d_ws;
  auto alloc = [&](size_t b) { char* r = p; p += (b + 255) & ~(size_t)255; return r; };
  float* deg     = (float*)alloc((size_t)N * 4);
  float* wdeg    = (float*)alloc((size_t)N * 4);
  int*   cnt     = (int*)alloc((size_t)N * 4);
  int*   ctr     = (int*)alloc(256);
  char*  zero_end = p;
  u16*   xbf     = (u16*)alloc((size_t)N * IN_C * 2);
  u16*   hbf     = (u16*)alloc((size_t)N * HID * 2);
  u16*   axhi    = (u16*)alloc((size_t)N * IN_C * 2);
  u16*   axlo    = (u16*)alloc((size_t)N * IN_C * 2);
  u16*   ahhi    = (u16*)alloc((size_t)N * HID * 2);
  u16*   ahlo    = (u16*)alloc((size_t)N * HID * 2);
  float* h2      = (float*)alloc((size_t)N * HID * 4);
  float* dis     = (float*)alloc((size_t)N * 4);
  u16*   w1hi    = (u16*)alloc((size_t)256 * 128 * 2);
  u16*   w1lo    = (u16*)alloc((size_t)256 * 128 * 2);
  u16*   w2hi    = (u16*)alloc((size_t)256 * 256 * 2);
  u16*   w2lo    = (u16*)alloc((size_t)256 * 256 * 2);
  int*   rowptr  = (int*)alloc((size_t)(N + 1) * 4);
  int*   rank    = (int*)alloc((size_t)E * 4);
  int*   col     = (int*)alloc((size_t)E * 4);
  float* coef    = (float*)alloc((size_t)E * 4);
  float* epart   = (float*)alloc((size_t)ER_BLOCKS * 4);
  float* pp      = (float*)alloc((size_t)pool_blocks * 33 * 4);
  if ((size_t)(p - (char*)d_ws) > ws_size) return;

  int zn4 = (int)((zero_end - (char*)deg) >> 4);
  zero_init<<<(zn4 + 255) / 256, 256, 0, stream>>>((int4*)deg, zn4);

  int eb = (E + 255) / 256;
  int nx4 = (N * IN_C) / 4;
  int conv_items = nx4 + 256 * 128 + 256 * 256;
  int cc_blocks = eb + (conv_items + 255) / 256;
  count_convert<<<cc_blocks, 256, 0, stream>>>(ei, ew, cnt, deg, wdeg, rank, E,
                                               x, xbf, nx4, W1, w1hi, w1lo,
                                               W2, w2hi, w2lo);
  scan_dis<<<1, 1024, 0, stream>>>(cnt, rowptr, deg, dis, N);
  scatter_edges<<<eb, 256, 0, stream>>>(ei, ew, rowptr, rank, dis, col, coef, E);

  dim3 gg((N + 63) / 64, HID / 64);
  aggregate_pre<128><<<(N + 3) / 4, 256, 0, stream>>>(xbf, rowptr, col, coef, deg, axhi, axlo, N);
  gemm_mfma<<<gg, 256, 0, stream>>>(axhi, axlo, w1hi, w1lo, b1, nullptr, hbf, N, IN_C, 1);
  aggregate_pre<256><<<(N + 3) / 4, 256, 0, stream>>>(hbf, rowptr, col, coef, deg, ahhi, ahlo, N);
  gemm_mfma<<<gg, 256, 0, stream>>>(ahhi, ahlo, w2hi, w2lo, b2, h2, nullptr, N, HID, 0);

  pool_kernel<<<pool_blocks, 256, 0, stream>>>(h2, Wp, bp, wdeg, out, pp, N);
  edge_reduce<<<ER_BLOCKS, 256, 0, stream>>>(ei, ew, out, epart, pp, pool_blocks,
                                             ctr, out, N, N * 16, E);
}

// Round 11
// 144.201 us; speedup vs baseline: 1.2397x; 1.2397x over previous
//
#include <hip/hip_runtime.h>
#include <math.h>

// ---------------------------------------------------------------------------
// DMoN pooling, edge-list formulation (dense adj never materialized).
//   0. zero_init: deg/wdeg/cnt
//   1. count_convert: per-edge cnt/deg/wdeg atomics (rank = atomic return),
//      narrow ei -> src32/dst32 ; x->bf16 ; W1,W2 -> transposed bf16 hi/lo
//   2. scan_dis: rowptr scan + dis = rsqrt(deg+1)
//   3. scatter: p = rowptr[dst] + rank[e]  (NO atomics)
//   4. layer 1: (axhi,axlo) = split(aggregate(x_bf)) ; h_bf = relu(ax@W1+b1)
//   5. layer 2: (ahhi,ahlo) = split(aggregate(h_bf)) ; h2 = relu(ah@W2+b2)
//      aggregates: block-per-node (R9: 16/8 edge streams, LDS reduce)
//   6. pool: s = softmax(h2@Wp+bp) -> d_out ; partials cs/ca/wsum
//   7. edge_reduce: tr partials, 2048 blocks (all edges in flight at once)
//   8. finalize: separate parallel reduction kernel, emit 3 scalars
// ---------------------------------------------------------------------------

#define ER_BLOCKS 2048

typedef unsigned short u16;
typedef __attribute__((ext_vector_type(8))) short short8v;
typedef __attribute__((ext_vector_type(4))) float float4v;
typedef __attribute__((ext_vector_type(4))) unsigned short ushort4v;
typedef __attribute__((ext_vector_type(8))) unsigned short ushort8v;

__device__ __forceinline__ u16 f2bf_rne(float x) {
  unsigned u = __float_as_uint(x);
  u = (u + 0x7fffu + ((u >> 16) & 1u)) >> 16;
  return (u16)u;
}
__device__ __forceinline__ float bf2f(u16 h) {
  return __uint_as_float(((unsigned)h) << 16);
}

// edge_index declared int64 in the reference, but JAX without x64 keeps int32.
__device__ __forceinline__ bool ei_is_i64(const int* __restrict__ ei) {
  return ((ei[1] | ei[3] | ei[5] | ei[7]) == 0);
}
__device__ __forceinline__ int ld_idx(const int* __restrict__ ei, int pos, bool i64) {
  return i64 ? ei[2 * pos] : ei[pos];
}

__global__ __launch_bounds__(256) void zero_init(int4* __restrict__ p, int n4) {
  int i = blockIdx.x * 256 + threadIdx.x;
  if (i < n4) p[i] = make_int4(0, 0, 0, 0);
}

// Blocks [0,eb): edge counting + ei narrowing. Blocks [eb,..): conversions.
__global__ __launch_bounds__(256) void count_convert(const int* __restrict__ ei,
                                                     const float* __restrict__ ew,
                                                     int* __restrict__ cnt,
                                                     float* __restrict__ deg,
                                                     float* __restrict__ wdeg,
                                                     int* __restrict__ rank,
                                                     int* __restrict__ src32,
                                                     int* __restrict__ dst32, int E,
                                                     const float* __restrict__ x,
                                                     u16* __restrict__ xbf, int nx4,
                                                     const float* __restrict__ W1,
                                                     u16* __restrict__ w1hi, u16* __restrict__ w1lo,
                                                     const float* __restrict__ W2,
                                                     u16* __restrict__ w2hi, u16* __restrict__ w2lo) {
  const int T1 = 256 * 128, T2 = 256 * 256;
  int eb = (E + 255) >> 8;
  int b = blockIdx.x;
  if (b < eb) {
    int e = b * 256 + threadIdx.x;
    if (e >= E) return;
    bool i64 = ei_is_i64(ei);
    int s = ld_idx(ei, e, i64);
    int d = ld_idx(ei, E + e, i64);
    float we = ew[e];
    src32[e] = s;
    dst32[e] = d;
    rank[e] = atomicAdd(&cnt[d], 1);  // rank within dst row
    atomicAdd(&deg[d], we);
    atomicAdd(&wdeg[s], we);
    return;
  }
  int idx = (b - eb) * 256 + threadIdx.x;
  if (idx < nx4) {
    float4 v = reinterpret_cast<const float4*>(x)[idx];
    ushort4v o = {f2bf_rne(v.x), f2bf_rne(v.y), f2bf_rne(v.z), f2bf_rne(v.w)};
    reinterpret_cast<ushort4v*>(xbf)[idx] = o;
    return;
  }
  idx -= nx4;
  if (idx < T1) {
    int n = idx >> 7, k = idx & 127;
    float v = W1[k * 256 + n];
    u16 h = f2bf_rne(v);
    w1hi[idx] = h;
    w1lo[idx] = f2bf_rne(v - bf2f(h));
    return;
  }
  idx -= T1;
  if (idx < T2) {
    int n = idx >> 8, k = idx & 255;
    float v = W2[k * 256 + n];
    u16 h = f2bf_rne(v);
    w2hi[idx] = h;
    w2lo[idx] = f2bf_rne(v - bf2f(h));
  }
}

// Single block: chunked scan cnt->rowptr, plus dis = rsqrt(deg+1).
__global__ __launch_bounds__(1024) void scan_dis(const int* __restrict__ cnt,
                                                 int* __restrict__ rowptr,
                                                 const float* __restrict__ deg,
                                                 float* __restrict__ dis, int n) {
  __shared__ int sums[1024];
  int tid = threadIdx.x;
  for (int i = tid; i < n; i += 1024) dis[i] = 1.0f / sqrtf(deg[i] + 1.0f);
  int CH = (n + 1023) >> 10;
  int beg = tid * CH, end = min(beg + CH, n);
  int s = 0;
  for (int i = beg; i < end; ++i) s += cnt[i];
  sums[tid] = s;
  __syncthreads();
  for (int off = 1; off < 1024; off <<= 1) {
    int v = (tid >= off) ? sums[tid - off] : 0;
    __syncthreads();
    sums[tid] += v;
    __syncthreads();
  }
  int run = (tid == 0) ? 0 : sums[tid - 1];
  for (int i = beg; i < end; ++i) { rowptr[i] = run; run += cnt[i]; }
  if (tid == 1023) rowptr[n] = run;
}

// Atomic-free scatter using precomputed rank and narrowed indices.
__global__ __launch_bounds__(256) void scatter_edges(const int* __restrict__ src32,
                                                     const int* __restrict__ dst32,
                                                     const float* __restrict__ ew,
                                                     const int* __restrict__ rowptr,
                                                     const int* __restrict__ rank,
                                                     const float* __restrict__ dis,
                                                     int* __restrict__ col,
                                                     float* __restrict__ coef, int E) {
  int e = blockIdx.x * 256 + threadIdx.x;
  if (e >= E) return;
  int s = src32[e];
  int d = dst32[e];
  int p = rowptr[d] + rank[e];
  col[p] = s;
  coef[p] = dis[s] * ew[e] * dis[d];
}

// Normalized aggregation: block-per-node, bf16 gather (16B/lane), fp32 accum,
// LDS cross-slot reduce, hi/lo output. (R9 structure — measured good.)
template <int CH>
__global__ __launch_bounds__(256) void aggregate_pre(const u16* __restrict__ src,
                                                     const int* __restrict__ rowptr,
                                                     const int* __restrict__ col,
                                                     const float* __restrict__ coef,
                                                     const float* __restrict__ deg,
                                                     u16* __restrict__ ohi,
                                                     u16* __restrict__ olo, int N) {
  constexpr int Q = CH / 8;    // ushort8 lanes per row (16 or 32)
  constexpr int NS = 256 / Q;  // concurrent edge slots (16 or 8)
  int i = blockIdx.x;
  int t = threadIdx.x;
  int q = t % Q, slot = t / Q;
  int e0 = rowptr[i], e1 = rowptr[i + 1];
  float a[8] = {};
  for (int p = e0 + slot; p < e1; p += NS) {
    int c = col[p];
    float w = coef[p];
    ushort8v v = *reinterpret_cast<const ushort8v*>(&src[(size_t)c * CH + q * 8]);
#pragma unroll
    for (int j = 0; j < 8; ++j) a[j] += w * bf2f(v[j]);
  }
  __shared__ float red[256][9];  // +1 pad: spread banks
#pragma unroll
  for (int j = 0; j < 8; ++j) red[t][j] = a[j];
  __syncthreads();
  if (slot == 0) {
#pragma unroll
    for (int s2 = 1; s2 < NS; ++s2)
#pragma unroll
      for (int j = 0; j < 8; ++j) a[j] += red[s2 * Q + q][j];
    float w0 = 1.0f / (deg[i] + 1.0f);  // self-loop term
    ushort8v xv = *reinterpret_cast<const ushort8v*>(&src[(size_t)i * CH + q * 8]);
    ushort8v hv, lv;
#pragma unroll
    for (int j = 0; j < 8; ++j) {
      a[j] += w0 * bf2f(xv[j]);
      u16 h = f2bf_rne(a[j]);
      hv[j] = h;
      lv[j] = f2bf_rne(a[j] - bf2f(h));
    }
    *reinterpret_cast<ushort8v*>(&ohi[(size_t)i * CH + q * 8]) = hv;
    *reinterpret_cast<ushort8v*>(&olo[(size_t)i * CH + q * 8]) = lv;
  }
}

// C[M,256] = relu(A@B + bias) via 3-term bf16 MFMA (A=Ahi+Alo, B=Bhi+Blo).
__global__ __launch_bounds__(256) void gemm_mfma(const u16* __restrict__ Ahi,
                                                 const u16* __restrict__ Alo,
                                                 const u16* __restrict__ Wthi,
                                                 const u16* __restrict__ Wtlo,
                                                 const float* __restrict__ bias,
                                                 float* __restrict__ C,
                                                 u16* __restrict__ Cbf,
                                                 int M, int K, int outbf) {
  __shared__ u16 As_hi[64][40], As_lo[64][40];
  __shared__ u16 Bs_hi[64][40], Bs_lo[64][40];
  int tid = threadIdx.x;
  int w = tid >> 6, l = tid & 63;
  int wm = w >> 1, wn = w & 1;
  int row0 = blockIdx.x * 64, col0 = blockIdx.y * 64;
  int srow = tid >> 2, sc = (tid & 3) * 8;
  int fr = l & 15, kg = (l >> 4) * 8;

  float4v acc[2][2];
#pragma unroll
  for (int i = 0; i < 2; ++i)
#pragma unroll
    for (int j = 0; j < 2; ++j) acc[i][j] = (float4v){0.f, 0.f, 0.f, 0.f};

  for (int k0 = 0; k0 < K; k0 += 32) {
    {
      int gr = row0 + srow;
      uint4 zero = make_uint4(0, 0, 0, 0);
      uint4 vh = zero, vl = zero;
      if (gr < M) {
        vh = *reinterpret_cast<const uint4*>(&Ahi[(size_t)gr * K + k0 + sc]);
        vl = *reinterpret_cast<const uint4*>(&Alo[(size_t)gr * K + k0 + sc]);
      }
      *reinterpret_cast<uint4*>(&As_hi[srow][sc]) = vh;
      *reinterpret_cast<uint4*>(&As_lo[srow][sc]) = vl;
      int bn = col0 + srow;
      uint4 bh = *reinterpret_cast<const uint4*>(&Wthi[(size_t)bn * K + k0 + sc]);
      uint4 bl = *reinterpret_cast<const uint4*>(&Wtlo[(size_t)bn * K + k0 + sc]);
      *reinterpret_cast<uint4*>(&Bs_hi[srow][sc]) = bh;
      *reinterpret_cast<uint4*>(&Bs_lo[srow][sc]) = bl;
    }
    __syncthreads();
    short8v ah[2], al[2], bh[2], bl[2];
#pragma unroll
    for (int i = 0; i < 2; ++i) {
      int r = wm * 32 + i * 16 + fr;
      ah[i] = *reinterpret_cast<const short8v*>(&As_hi[r][kg]);
      al[i] = *reinterpret_cast<const short8v*>(&As_lo[r][kg]);
    }
#pragma unroll
    for (int j = 0; j < 2; ++j) {
      int n = wn * 32 + j * 16 + fr;
      bh[j] = *reinterpret_cast<const short8v*>(&Bs_hi[n][kg]);
      bl[j] = *reinterpret_cast<const short8v*>(&Bs_lo[n][kg]);
    }
#pragma unroll
    for (int i = 0; i < 2; ++i)
#pragma unroll
      for (int j = 0; j < 2; ++j) {
        acc[i][j] = __builtin_amdgcn_mfma_f32_16x16x32_bf16(ah[i], bh[j], acc[i][j], 0, 0, 0);
        acc[i][j] = __builtin_amdgcn_mfma_f32_16x16x32_bf16(al[i], bh[j], acc[i][j], 0, 0, 0);
        acc[i][j] = __builtin_amdgcn_mfma_f32_16x16x32_bf16(ah[i], bl[j], acc[i][j], 0, 0, 0);
      }
    __syncthreads();
  }
#pragma unroll
  for (int j = 0; j < 2; ++j) {
    int gc = col0 + wn * 32 + j * 16 + fr;
    float bj = bias[gc];
#pragma unroll
    for (int i = 0; i < 2; ++i) {
#pragma unroll
      for (int r = 0; r < 4; ++r) {
        int gr = row0 + wm * 32 + i * 16 + (l >> 4) * 4 + r;
        if (gr < M) {
          float v = fmaxf(acc[i][j][r] + bj, 0.0f);
          if (outbf) Cbf[(size_t)gr * 256 + gc] = f2bf_rne(v);
          else       C[(size_t)gr * 256 + gc] = v;
        }
      }
    }
  }
}

// Pooling + softmax; per-block partials: [0..15]=cs, [16..31]=ca, [32]=wsum.
__global__ __launch_bounds__(256) void pool_kernel(const float* __restrict__ h,
                                                   const float* __restrict__ Wp,
                                                   const float* __restrict__ bp,
                                                   const float* __restrict__ wdeg,
                                                   float* __restrict__ s_out,
                                                   float* __restrict__ pp, int N) {
  __shared__ float Wps[256 * 16];
  __shared__ float loc[33];
  int tid = threadIdx.x;
  for (int idx = tid; idx < 4096; idx += 256) Wps[idx] = Wp[idx];
  if (tid < 33) loc[tid] = 0.f;
  __syncthreads();
  int lane = tid & 63;
  int wave = tid >> 6;
  int k = lane & 15, g = lane >> 4;
  int node = blockIdx.x * 16 + wave * 4 + g;
  float acc = 0.f, wd = 0.f;
  if (node < N) {
    wd = wdeg[node];
    const float4* hrow = reinterpret_cast<const float4*>(h + (size_t)node * 256);
#pragma unroll 8
    for (int c4 = 0; c4 < 64; ++c4) {
      float4 hv = hrow[c4];
      int cb = c4 * 4;
      acc += hv.x * Wps[(cb + 0) * 16 + k];
      acc += hv.y * Wps[(cb + 1) * 16 + k];
      acc += hv.z * Wps[(cb + 2) * 16 + k];
      acc += hv.w * Wps[(cb + 3) * 16 + k];
    }
    acc += bp[k];
  }
  float mx = acc;
#pragma unroll
  for (int off = 1; off < 16; off <<= 1) mx = fmaxf(mx, __shfl_xor(mx, off));
  float ex = (node < N) ? expf(acc - mx) : 0.f;
  float sm = ex;
#pragma unroll
  for (int off = 1; off < 16; off <<= 1) sm += __shfl_xor(sm, off);
  float sval = (node < N) ? ex / sm : 0.f;
  if (node < N) s_out[(size_t)node * 16 + k] = sval;
  float v = sval;
  float v2 = wd * sval;
  float v3 = (k == 0) ? wd : 0.f;
  v += __shfl_xor(v, 16);  v += __shfl_xor(v, 32);
  v2 += __shfl_xor(v2, 16); v2 += __shfl_xor(v2, 32);
  v3 += __shfl_xor(v3, 16); v3 += __shfl_xor(v3, 32);
  if (lane < 16) {
    atomicAdd(&loc[lane], v);
    atomicAdd(&loc[16 + lane], v2);
  }
  if (lane == 0) atomicAdd(&loc[32], v3);
  __syncthreads();
  if (tid < 33) pp[(size_t)blockIdx.x * 33 + tid] = loc[tid];
}

// tr = SUM_e w*dot(s_src,s_dst); 4 lanes/edge; ~all edges in flight at once.
__global__ __launch_bounds__(256) void edge_reduce(const int* __restrict__ src32,
                                                   const int* __restrict__ dst32,
                                                   const float* __restrict__ ew,
                                                   const float* __restrict__ s,
                                                   float* __restrict__ part, int E) {
  int tid = threadIdx.x;
  int le = tid >> 2, sub = tid & 3;
  int epi = gridDim.x * 64;
  float acc = 0.f;
  for (int e = blockIdx.x * 64 + le; e < E; e += epi) {
    int a = src32[e];
    int b = dst32[e];
    float w = ew[e];
    float4 av = *reinterpret_cast<const float4*>(s + (size_t)a * 16 + sub * 4);
    float4 bv = *reinterpret_cast<const float4*>(s + (size_t)b * 16 + sub * 4);
    float d = av.x * bv.x + av.y * bv.y + av.z * bv.z + av.w * bv.w;
    d += __shfl_xor(d, 1);
    d += __shfl_xor(d, 2);
    acc += w * d;  // 4 lane-copies/group; xor-4+ reduce counts each group once
  }
#pragma unroll
  for (int off = 4; off < 64; off <<= 1) acc += __shfl_xor(acc, off);
  __shared__ float loc;
  if (tid == 0) loc = 0.f;
  __syncthreads();
  if ((tid & 63) == 0) atomicAdd(&loc, acc);
  __syncthreads();
  if (tid == 0) part[blockIdx.x] = loc;
}

// Parallel finalize: reduce ER_BLOCKS trace-partials + pb x 33 pool partials.
__global__ __launch_bounds__(256) void finalize(const float* __restrict__ epart,
                                                const float* __restrict__ pp, int pb,
                                                float* __restrict__ out,
                                                int N, int s_elems) {
  __shared__ float cred[256];
  __shared__ float vals[32];
  __shared__ float scal[2];  // [0]=tr, [1]=wsum
  int tid = threadIdx.x;
  float a = 0.f;
  for (int b = tid; b < ER_BLOCKS; b += 256) a += epart[b];
  float wv = 0.f;
  for (int b = tid; b < pb; b += 256) wv += pp[(size_t)b * 33 + 32];
#pragma unroll
  for (int off = 1; off < 64; off <<= 1) {
    a += __shfl_xor(a, off);
    wv += __shfl_xor(wv, off);
  }
  if (tid == 0) { scal[0] = 0.f; scal[1] = 0.f; }
  __syncthreads();
  if ((tid & 63) == 0) {
    atomicAdd(&scal[0], a);
    atomicAdd(&scal[1], wv);
  }
  {
    int k = tid & 31, sl = tid >> 5;
    float c = 0.f;
    for (int b = sl; b < pb; b += 8) c += pp[(size_t)b * 33 + k];
    cred[tid] = c;
  }
  __syncthreads();
  if (tid < 32) {
    float c = cred[tid];
#pragma unroll
    for (int sl = 1; sl < 8; ++sl) c += cred[sl * 32 + tid];
    vals[tid] = c;
  }
  __syncthreads();
  if (tid == 0) {
    float tr = scal[0], m2 = scal[1];
    float ca2 = 0.f, cs2 = 0.f;
    for (int k = 0; k < 16; ++k) {
      cs2 += vals[k] * vals[k];
      ca2 += vals[16 + k] * vals[16 + k];
    }
    float sp = -(tr - ca2 / m2) / m2;
    float cl = sqrtf(cs2) / (float)N * 4.0f - 1.0f;
    out[s_elems + 0] = 100.f * (sp + cl);
    out[s_elems + 1] = 100.f * sp;
    out[s_elems + 2] = 100.f * cl;
  }
}

extern "C" void kernel_launch(void* const* d_in, const int* in_sizes, int n_in,
                              void* d_out, int out_size, void* d_ws, size_t ws_size,
                              hipStream_t stream) {
  const float* x  = (const float*)d_in[0];
  const int*   ei = (const int*)d_in[1];
  const float* ew = (const float*)d_in[2];
  const float* W1 = (const float*)d_in[3];
  const float* b1 = (const float*)d_in[4];
  const float* W2 = (const float*)d_in[5];
  const float* b2 = (const float*)d_in[6];
  const float* Wp = (const float*)d_in[7];
  const float* bp = (const float*)d_in[8];
  float* out = (float*)d_out;

  const int IN_C = 128, HID = 256;
  const int N = in_sizes[0] / IN_C;   // 10000
  const int E = in_sizes[2];          // 160000
  const int pool_blocks = (N + 15) / 16;

  char* p = (char*)d_ws;
  auto alloc = [&](size_t b) { char* r = p; p += (b + 255) & ~(size_t)255; return r; };
  float* deg     = (float*)alloc((size_t)N * 4);
  float* wdeg    = (float*)alloc((size_t)N * 4);
  int*   cnt     = (int*)alloc((size_t)N * 4);
  char*  zero_end = p;
  u16*   xbf     = (u16*)alloc((size_t)N * IN_C * 2);
  u16*   hbf     = (u16*)alloc((size_t)N * HID * 2);
  u16*   axhi    = (u16*)alloc((size_t)N * IN_C * 2);
  u16*   axlo    = (u16*)alloc((size_t)N * IN_C * 2);
  u16*   ahhi    = (u16*)alloc((size_t)N * HID * 2);
  u16*   ahlo    = (u16*)alloc((size_t)N * HID * 2);
  float* h2      = (float*)alloc((size_t)N * HID * 4);
  float* dis     = (float*)alloc((size_t)N * 4);
  u16*   w1hi    = (u16*)alloc((size_t)256 * 128 * 2);
  u16*   w1lo    = (u16*)alloc((size_t)256 * 128 * 2);
  u16*   w2hi    = (u16*)alloc((size_t)256 * 256 * 2);
  u16*   w2lo    = (u16*)alloc((size_t)256 * 256 * 2);
  int*   rowptr  = (int*)alloc((size_t)(N + 1) * 4);
  int*   rank    = (int*)alloc((size_t)E * 4);
  int*   src32   = (int*)alloc((size_t)E * 4);
  int*   dst32   = (int*)alloc((size_t)E * 4);
  int*   col     = (int*)alloc((size_t)E * 4);
  float* coef    = (float*)alloc((size_t)E * 4);
  float* epart   = (float*)alloc((size_t)ER_BLOCKS * 4);
  float* pp      = (float*)alloc((size_t)pool_blocks * 33 * 4);
  if ((size_t)(p - (char*)d_ws) > ws_size) return;

  int zn4 = (int)((zero_end - (char*)deg) >> 4);
  zero_init<<<(zn4 + 255) / 256, 256, 0, stream>>>((int4*)deg, zn4);

  int eb = (E + 255) / 256;
  int nx4 = (N * IN_C) / 4;
  int conv_items = nx4 + 256 * 128 + 256 * 256;
  int cc_blocks = eb + (conv_items + 255) / 256;
  count_convert<<<cc_blocks, 256, 0, stream>>>(ei, ew, cnt, deg, wdeg, rank,
                                               src32, dst32, E,
                                               x, xbf, nx4, W1, w1hi, w1lo,
                                               W2, w2hi, w2lo);
  scan_dis<<<1, 1024, 0, stream>>>(cnt, rowptr, deg, dis, N);
  scatter_edges<<<eb, 256, 0, stream>>>(src32, dst32, ew, rowptr, rank, dis,
                                        col, coef, E);

  dim3 gg((N + 63) / 64, HID / 64);
  aggregate_pre<128><<<N, 256, 0, stream>>>(xbf, rowptr, col, coef, deg, axhi, axlo, N);
  gemm_mfma<<<gg, 256, 0, stream>>>(axhi, axlo, w1hi, w1lo, b1, nullptr, hbf, N, IN_C, 1);
  aggregate_pre<256><<<N, 256, 0, stream>>>(hbf, rowptr, col, coef, deg, ahhi, ahlo, N);
  gemm_mfma<<<gg, 256, 0, stream>>>(ahhi, ahlo, w2hi, w2lo, b2, h2, nullptr, N, HID, 0);

  pool_kernel<<<pool_blocks, 256, 0, stream>>>(h2, Wp, bp, wdeg, out, pp, N);
  edge_reduce<<<ER_BLOCKS, 256, 0, stream>>>(src32, dst32, ew, out, epart, E);
  finalize<<<1, 256, 0, stream>>>(epart, pp, pool_blocks, out, N, N * 16);
}

// Round 12
// 139.421 us; speedup vs baseline: 1.2822x; 1.0343x over previous
//
#include <hip/hip_runtime.h>
#include <math.h>

// ---------------------------------------------------------------------------
// DMoN pooling, edge-list formulation (dense adj never materialized).
//   0. zero_init: cd (packed cnt|deg) / wdeg
//   1. count_convert: ONE 64-bit atomic per edge to cd[dst]
//      (hi32 = count -> rank from return; lo32 = deg in 2^-24 fixed point),
//      + wdeg[src] atomic ; narrow ei -> src32/dst32 ; x->bf16 ; W1,W2 hi/lo
//   2. scan_dis: rowptr scan (cd hi) + dis = rsqrt(deg+1) (cd lo)
//   3. scatter: p = rowptr[dst] + rank[e]  (NO atomics)
//   4. layer 1: (axhi,axlo) = split(aggregate(x_bf)) ; h_bf = relu(ax@W1+b1)
//   5. layer 2: (ahhi,ahlo) = split(aggregate(h_bf)) ; h2_bf = relu(ah@W2+b2)
//      aggregates: block-per-node, self-loop weight = dis[i]^2
//   6. pool: s = softmax(h2_bf@Wp+bp) -> d_out ; partials cs/ca/wsum
//   7. edge_reduce: tr partials (2048 blocks)
//   8. finalize: parallel reduction, emit 3 scalars
// ---------------------------------------------------------------------------

#define ER_BLOCKS 2048

typedef unsigned short u16;
typedef unsigned long long u64;
typedef __attribute__((ext_vector_type(8))) short short8v;
typedef __attribute__((ext_vector_type(4))) float float4v;
typedef __attribute__((ext_vector_type(4))) unsigned short ushort4v;
typedef __attribute__((ext_vector_type(8))) unsigned short ushort8v;

#define DEG_SCALE 16777216.0f  // 2^24 fixed-point for packed deg

__device__ __forceinline__ u16 f2bf_rne(float x) {
  unsigned u = __float_as_uint(x);
  u = (u + 0x7fffu + ((u >> 16) & 1u)) >> 16;
  return (u16)u;
}
__device__ __forceinline__ float bf2f(u16 h) {
  return __uint_as_float(((unsigned)h) << 16);
}

// edge_index declared int64 in the reference, but JAX without x64 keeps int32.
__device__ __forceinline__ bool ei_is_i64(const int* __restrict__ ei) {
  return ((ei[1] | ei[3] | ei[5] | ei[7]) == 0);
}
__device__ __forceinline__ int ld_idx(const int* __restrict__ ei, int pos, bool i64) {
  return i64 ? ei[2 * pos] : ei[pos];
}

__global__ __launch_bounds__(256) void zero_init(int4* __restrict__ p, int n4) {
  int i = blockIdx.x * 256 + threadIdx.x;
  if (i < n4) p[i] = make_int4(0, 0, 0, 0);
}

// Blocks [0,eb): edge counting (ONE packed 64-bit atomic to dst) + narrowing.
// Blocks [eb,..): x->bf16, W1/W2 -> [n][k] bf16 hi/lo conversions.
__global__ __launch_bounds__(256) void count_convert(const int* __restrict__ ei,
                                                     const float* __restrict__ ew,
                                                     u64* __restrict__ cd,
                                                     float* __restrict__ wdeg,
                                                     int* __restrict__ rank,
                                                     int* __restrict__ src32,
                                                     int* __restrict__ dst32, int E,
                                                     const float* __restrict__ x,
                                                     u16* __restrict__ xbf, int nx4,
                                                     const float* __restrict__ W1,
                                                     u16* __restrict__ w1hi, u16* __restrict__ w1lo,
                                                     const float* __restrict__ W2,
                                                     u16* __restrict__ w2hi, u16* __restrict__ w2lo) {
  const int T1 = 256 * 128, T2 = 256 * 256;
  int eb = (E + 255) >> 8;
  int b = blockIdx.x;
  if (b < eb) {
    int e = b * 256 + threadIdx.x;
    if (e >= E) return;
    bool i64 = ei_is_i64(ei);
    int s = ld_idx(ei, e, i64);
    int d = ld_idx(ei, E + e, i64);
    float we = ew[e];
    src32[e] = s;
    dst32[e] = d;
    u64 pack = (1ULL << 32) | (u64)__float2uint_rn(we * DEG_SCALE);
    u64 old = atomicAdd(&cd[d], pack);
    rank[e] = (int)(old >> 32);
    atomicAdd(&wdeg[s], we);
    return;
  }
  int idx = (b - eb) * 256 + threadIdx.x;
  if (idx < nx4) {
    float4 v = reinterpret_cast<const float4*>(x)[idx];
    ushort4v o = {f2bf_rne(v.x), f2bf_rne(v.y), f2bf_rne(v.z), f2bf_rne(v.w)};
    reinterpret_cast<ushort4v*>(xbf)[idx] = o;
    return;
  }
  idx -= nx4;
  if (idx < T1) {
    int n = idx >> 7, k = idx & 127;
    float v = W1[k * 256 + n];
    u16 h = f2bf_rne(v);
    w1hi[idx] = h;
    w1lo[idx] = f2bf_rne(v - bf2f(h));
    return;
  }
  idx -= T1;
  if (idx < T2) {
    int n = idx >> 8, k = idx & 255;
    float v = W2[k * 256 + n];
    u16 h = f2bf_rne(v);
    w2hi[idx] = h;
    w2lo[idx] = f2bf_rne(v - bf2f(h));
  }
}

// Single block: chunked scan (cd high words) -> rowptr; dis from cd low words.
__global__ __launch_bounds__(1024) void scan_dis(const u64* __restrict__ cd,
                                                 int* __restrict__ rowptr,
                                                 float* __restrict__ dis, int n) {
  __shared__ int sums[1024];
  int tid = threadIdx.x;
  for (int i = tid; i < n; i += 1024) {
    float degi = (float)(unsigned)(cd[i] & 0xFFFFFFFFull) * (1.0f / DEG_SCALE);
    dis[i] = 1.0f / sqrtf(degi + 1.0f);  // +1 = self-loop weight
  }
  int CH = (n + 1023) >> 10;
  int beg = tid * CH, end = min(beg + CH, n);
  int s = 0;
  for (int i = beg; i < end; ++i) s += (int)(cd[i] >> 32);
  sums[tid] = s;
  __syncthreads();
  for (int off = 1; off < 1024; off <<= 1) {
    int v = (tid >= off) ? sums[tid - off] : 0;
    __syncthreads();
    sums[tid] += v;
    __syncthreads();
  }
  int run = (tid == 0) ? 0 : sums[tid - 1];
  for (int i = beg; i < end; ++i) { rowptr[i] = run; run += (int)(cd[i] >> 32); }
  if (tid == 1023) rowptr[n] = run;
}

// Atomic-free scatter using precomputed rank and narrowed indices.
__global__ __launch_bounds__(256) void scatter_edges(const int* __restrict__ src32,
                                                     const int* __restrict__ dst32,
                                                     const float* __restrict__ ew,
                                                     const int* __restrict__ rowptr,
                                                     const int* __restrict__ rank,
                                                     const float* __restrict__ dis,
                                                     int* __restrict__ col,
                                                     float* __restrict__ coef, int E) {
  int e = blockIdx.x * 256 + threadIdx.x;
  if (e >= E) return;
  int s = src32[e];
  int d = dst32[e];
  int p = rowptr[d] + rank[e];
  col[p] = s;
  coef[p] = dis[s] * ew[e] * dis[d];
}

// Normalized aggregation: block-per-node, bf16 gather (16B/lane), fp32 accum,
// LDS cross-slot reduce, hi/lo output. Self-loop weight = dis[i]^2.
template <int CH>
__global__ __launch_bounds__(256) void aggregate_pre(const u16* __restrict__ src,
                                                     const int* __restrict__ rowptr,
                                                     const int* __restrict__ col,
                                                     const float* __restrict__ coef,
                                                     const float* __restrict__ dis,
                                                     u16* __restrict__ ohi,
                                                     u16* __restrict__ olo, int N) {
  constexpr int Q = CH / 8;    // ushort8 lanes per row (16 or 32)
  constexpr int NS = 256 / Q;  // concurrent edge slots (16 or 8)
  int i = blockIdx.x;
  int t = threadIdx.x;
  int q = t % Q, slot = t / Q;
  int e0 = rowptr[i], e1 = rowptr[i + 1];
  float a[8] = {};
  for (int p = e0 + slot; p < e1; p += NS) {
    int c = col[p];
    float w = coef[p];
    ushort8v v = *reinterpret_cast<const ushort8v*>(&src[(size_t)c * CH + q * 8]);
#pragma unroll
    for (int j = 0; j < 8; ++j) a[j] += w * bf2f(v[j]);
  }
  __shared__ float red[256][9];  // +1 pad: spread banks
#pragma unroll
  for (int j = 0; j < 8; ++j) red[t][j] = a[j];
  __syncthreads();
  if (slot == 0) {
#pragma unroll
    for (int s2 = 1; s2 < NS; ++s2)
#pragma unroll
      for (int j = 0; j < 8; ++j) a[j] += red[s2 * Q + q][j];
    float di = dis[i];
    float w0 = di * di;  // == 1/(deg+1): self-loop coefficient
    ushort8v xv = *reinterpret_cast<const ushort8v*>(&src[(size_t)i * CH + q * 8]);
    ushort8v hv, lv;
#pragma unroll
    for (int j = 0; j < 8; ++j) {
      a[j] += w0 * bf2f(xv[j]);
      u16 h = f2bf_rne(a[j]);
      hv[j] = h;
      lv[j] = f2bf_rne(a[j] - bf2f(h));
    }
    *reinterpret_cast<ushort8v*>(&ohi[(size_t)i * CH + q * 8]) = hv;
    *reinterpret_cast<ushort8v*>(&olo[(size_t)i * CH + q * 8]) = lv;
  }
}

// C[M,256] = relu(A@B + bias) via 3-term bf16 MFMA (A=Ahi+Alo, B=Bhi+Blo).
// Output always bf16.
__global__ __launch_bounds__(256) void gemm_mfma(const u16* __restrict__ Ahi,
                                                 const u16* __restrict__ Alo,
                                                 const u16* __restrict__ Wthi,
                                                 const u16* __restrict__ Wtlo,
                                                 const float* __restrict__ bias,
                                                 u16* __restrict__ Cbf,
                                                 int M, int K) {
  __shared__ u16 As_hi[64][40], As_lo[64][40];
  __shared__ u16 Bs_hi[64][40], Bs_lo[64][40];
  int tid = threadIdx.x;
  int w = tid >> 6, l = tid & 63;
  int wm = w >> 1, wn = w & 1;
  int row0 = blockIdx.x * 64, col0 = blockIdx.y * 64;
  int srow = tid >> 2, sc = (tid & 3) * 8;
  int fr = l & 15, kg = (l >> 4) * 8;

  float4v acc[2][2];
#pragma unroll
  for (int i = 0; i < 2; ++i)
#pragma unroll
    for (int j = 0; j < 2; ++j) acc[i][j] = (float4v){0.f, 0.f, 0.f, 0.f};

  for (int k0 = 0; k0 < K; k0 += 32) {
    {
      int gr = row0 + srow;
      uint4 zero = make_uint4(0, 0, 0, 0);
      uint4 vh = zero, vl = zero;
      if (gr < M) {
        vh = *reinterpret_cast<const uint4*>(&Ahi[(size_t)gr * K + k0 + sc]);
        vl = *reinterpret_cast<const uint4*>(&Alo[(size_t)gr * K + k0 + sc]);
      }
      *reinterpret_cast<uint4*>(&As_hi[srow][sc]) = vh;
      *reinterpret_cast<uint4*>(&As_lo[srow][sc]) = vl;
      int bn = col0 + srow;
      uint4 bh = *reinterpret_cast<const uint4*>(&Wthi[(size_t)bn * K + k0 + sc]);
      uint4 bl = *reinterpret_cast<const uint4*>(&Wtlo[(size_t)bn * K + k0 + sc]);
      *reinterpret_cast<uint4*>(&Bs_hi[srow][sc]) = bh;
      *reinterpret_cast<uint4*>(&Bs_lo[srow][sc]) = bl;
    }
    __syncthreads();
    short8v ah[2], al[2], bh[2], bl[2];
#pragma unroll
    for (int i = 0; i < 2; ++i) {
      int r = wm * 32 + i * 16 + fr;
      ah[i] = *reinterpret_cast<const short8v*>(&As_hi[r][kg]);
      al[i] = *reinterpret_cast<const short8v*>(&As_lo[r][kg]);
    }
#pragma unroll
    for (int j = 0; j < 2; ++j) {
      int n = wn * 32 + j * 16 + fr;
      bh[j] = *reinterpret_cast<const short8v*>(&Bs_hi[n][kg]);
      bl[j] = *reinterpret_cast<const short8v*>(&Bs_lo[n][kg]);
    }
#pragma unroll
    for (int i = 0; i < 2; ++i)
#pragma unroll
      for (int j = 0; j < 2; ++j) {
        acc[i][j] = __builtin_amdgcn_mfma_f32_16x16x32_bf16(ah[i], bh[j], acc[i][j], 0, 0, 0);
        acc[i][j] = __builtin_amdgcn_mfma_f32_16x16x32_bf16(al[i], bh[j], acc[i][j], 0, 0, 0);
        acc[i][j] = __builtin_amdgcn_mfma_f32_16x16x32_bf16(ah[i], bl[j], acc[i][j], 0, 0, 0);
      }
    __syncthreads();
  }
#pragma unroll
  for (int j = 0; j < 2; ++j) {
    int gc = col0 + wn * 32 + j * 16 + fr;
    float bj = bias[gc];
#pragma unroll
    for (int i = 0; i < 2; ++i) {
#pragma unroll
      for (int r = 0; r < 4; ++r) {
        int gr = row0 + wm * 32 + i * 16 + (l >> 4) * 4 + r;
        if (gr < M) {
          float v = fmaxf(acc[i][j][r] + bj, 0.0f);
          Cbf[(size_t)gr * 256 + gc] = f2bf_rne(v);
        }
      }
    }
  }
}

// Pooling + softmax from bf16 h; per-block partials [0..15]=cs [16..31]=ca [32]=wsum.
__global__ __launch_bounds__(256) void pool_kernel(const u16* __restrict__ h,
                                                   const float* __restrict__ Wp,
                                                   const float* __restrict__ bp,
                                                   const float* __restrict__ wdeg,
                                                   float* __restrict__ s_out,
                                                   float* __restrict__ pp, int N) {
  __shared__ float Wps[256 * 16];
  __shared__ float loc[33];
  int tid = threadIdx.x;
  for (int idx = tid; idx < 4096; idx += 256) Wps[idx] = Wp[idx];
  if (tid < 33) loc[tid] = 0.f;
  __syncthreads();
  int lane = tid & 63;
  int wave = tid >> 6;
  int k = lane & 15, g = lane >> 4;
  int node = blockIdx.x * 16 + wave * 4 + g;
  float acc = 0.f, wd = 0.f;
  if (node < N) {
    wd = wdeg[node];
    const ushort8v* hrow = reinterpret_cast<const ushort8v*>(h + (size_t)node * 256);
#pragma unroll 8
    for (int c8 = 0; c8 < 32; ++c8) {
      ushort8v hv = hrow[c8];
      int cb = c8 * 8;
#pragma unroll
      for (int j = 0; j < 8; ++j) acc += bf2f(hv[j]) * Wps[(cb + j) * 16 + k];
    }
    acc += bp[k];
  }
  float mx = acc;
#pragma unroll
  for (int off = 1; off < 16; off <<= 1) mx = fmaxf(mx, __shfl_xor(mx, off));
  float ex = (node < N) ? expf(acc - mx) : 0.f;
  float sm = ex;
#pragma unroll
  for (int off = 1; off < 16; off <<= 1) sm += __shfl_xor(sm, off);
  float sval = (node < N) ? ex / sm : 0.f;
  if (node < N) s_out[(size_t)node * 16 + k] = sval;
  float v = sval;
  float v2 = wd * sval;
  float v3 = (k == 0) ? wd : 0.f;
  v += __shfl_xor(v, 16);  v += __shfl_xor(v, 32);
  v2 += __shfl_xor(v2, 16); v2 += __shfl_xor(v2, 32);
  v3 += __shfl_xor(v3, 16); v3 += __shfl_xor(v3, 32);
  if (lane < 16) {
    atomicAdd(&loc[lane], v);
    atomicAdd(&loc[16 + lane], v2);
  }
  if (lane == 0) atomicAdd(&loc[32], v3);
  __syncthreads();
  if (tid < 33) pp[(size_t)blockIdx.x * 33 + tid] = loc[tid];
}

// tr = SUM_e w*dot(s_src,s_dst); 4 lanes/edge; ~all edges in flight at once.
__global__ __launch_bounds__(256) void edge_reduce(const int* __restrict__ src32,
                                                   const int* __restrict__ dst32,
                                                   const float* __restrict__ ew,
                                                   const float* __restrict__ s,
                                                   float* __restrict__ part, int E) {
  int tid = threadIdx.x;
  int le = tid >> 2, sub = tid & 3;
  int epi = gridDim.x * 64;
  float acc = 0.f;
  for (int e = blockIdx.x * 64 + le; e < E; e += epi) {
    int a = src32[e];
    int b = dst32[e];
    float w = ew[e];
    float4 av = *reinterpret_cast<const float4*>(s + (size_t)a * 16 + sub * 4);
    float4 bv = *reinterpret_cast<const float4*>(s + (size_t)b * 16 + sub * 4);
    float d = av.x * bv.x + av.y * bv.y + av.z * bv.z + av.w * bv.w;
    d += __shfl_xor(d, 1);
    d += __shfl_xor(d, 2);
    acc += w * d;  // 4 lane-copies/group; xor-4+ reduce counts each group once
  }
#pragma unroll
  for (int off = 4; off < 64; off <<= 1) acc += __shfl_xor(acc, off);
  __shared__ float loc;
  if (tid == 0) loc = 0.f;
  __syncthreads();
  if ((tid & 63) == 0) atomicAdd(&loc, acc);
  __syncthreads();
  if (tid == 0) part[blockIdx.x] = loc;
}

// Parallel finalize: reduce ER_BLOCKS trace-partials + pb x 33 pool partials.
__global__ __launch_bounds__(256) void finalize(const float* __restrict__ epart,
                                                const float* __restrict__ pp, int pb,
                                                float* __restrict__ out,
                                                int N, int s_elems) {
  __shared__ float cred[256];
  __shared__ float vals[32];
  __shared__ float scal[2];  // [0]=tr, [1]=wsum
  int tid = threadIdx.x;
  float a = 0.f;
  for (int b = tid; b < ER_BLOCKS; b += 256) a += epart[b];
  float wv = 0.f;
  for (int b = tid; b < pb; b += 256) wv += pp[(size_t)b * 33 + 32];
#pragma unroll
  for (int off = 1; off < 64; off <<= 1) {
    a += __shfl_xor(a, off);
    wv += __shfl_xor(wv, off);
  }
  if (tid == 0) { scal[0] = 0.f; scal[1] = 0.f; }
  __syncthreads();
  if ((tid & 63) == 0) {
    atomicAdd(&scal[0], a);
    atomicAdd(&scal[1], wv);
  }
  {
    int k = tid & 31, sl = tid >> 5;
    float c = 0.f;
    for (int b = sl; b < pb; b += 8) c += pp[(size_t)b * 33 + k];
    cred[tid] = c;
  }
  __syncthreads();
  if (tid < 32) {
    float c = cred[tid];
#pragma unroll
    for (int sl = 1; sl < 8; ++sl) c += cred[sl * 32 + tid];
    vals[tid] = c;
  }
  __syncthreads();
  if (tid == 0) {
    float tr = scal[0], m2 = scal[1];
    float ca2 = 0.f, cs2 = 0.f;
    for (int k = 0; k < 16; ++k) {
      cs2 += vals[k] * vals[k];
      ca2 += vals[16 + k] * vals[16 + k];
    }
    float sp = -(tr - ca2 / m2) / m2;
    float cl = sqrtf(cs2) / (float)N * 4.0f - 1.0f;
    out[s_elems + 0] = 100.f * (sp + cl);
    out[s_elems + 1] = 100.f * sp;
    out[s_elems + 2] = 100.f * cl;
  }
}

extern "C" void kernel_launch(void* const* d_in, const int* in_sizes, int n_in,
                              void* d_out, int out_size, void* d_ws, size_t ws_size,
                              hipStream_t stream) {
  const float* x  = (const float*)d_in[0];
  const int*   ei = (const int*)d_in[1];
  const float* ew = (const float*)d_in[2];
  const float* W1 = (const float*)d_in[3];
  const float* b1 = (const float*)d_in[4];
  const float* W2 = (const float*)d_in[5];
  const float* b2 = (const float*)d_in[6];
  const float* Wp = (const float*)d_in[7];
  const float* bp = (const float*)d_in[8];
  float* out = (float*)d_out;

  const int IN_C = 128, HID = 256;
  const int N = in_sizes[0] / IN_C;   // 10000
  const int E = in_sizes[2];          // 160000
  const int pool_blocks = (N + 15) / 16;

  char* p = (char*)d_ws;
  auto alloc = [&](size_t b) { char* r = p; p += (b + 255) & ~(size_t)255; return r; };
  u64*   cd      = (u64*)alloc((size_t)N * 8);    // packed cnt|deg
  float* wdeg    = (float*)alloc((size_t)N * 4);
  char*  zero_end = p;
  u16*   xbf     = (u16*)alloc((size_t)N * IN_C * 2);
  u16*   hbf     = (u16*)alloc((size_t)N * HID * 2);
  u16*   hbf2    = (u16*)alloc((size_t)N * HID * 2);
  u16*   axhi    = (u16*)alloc((size_t)N * IN_C * 2);
  u16*   axlo    = (u16*)alloc((size_t)N * IN_C * 2);
  u16*   ahhi    = (u16*)alloc((size_t)N * HID * 2);
  u16*   ahlo    = (u16*)alloc((size_t)N * HID * 2);
  float* dis     = (float*)alloc((size_t)N * 4);
  u16*   w1hi    = (u16*)alloc((size_t)256 * 128 * 2);
  u16*   w1lo    = (u16*)alloc((size_t)256 * 128 * 2);
  u16*   w2hi    = (u16*)alloc((size_t)256 * 256 * 2);
  u16*   w2lo    = (u16*)alloc((size_t)256 * 256 * 2);
  int*   rowptr  = (int*)alloc((size_t)(N + 1) * 4);
  int*   rank    = (int*)alloc((size_t)E * 4);
  int*   src32   = (int*)alloc((size_t)E * 4);
  int*   dst32   = (int*)alloc((size_t)E * 4);
  int*   col     = (int*)alloc((size_t)E * 4);
  float* coef    = (float*)alloc((size_t)E * 4);
  float* epart   = (float*)alloc((size_t)ER_BLOCKS * 4);
  float* pp      = (float*)alloc((size_t)pool_blocks * 33 * 4);
  if ((size_t)(p - (char*)d_ws) > ws_size) return;

  int zn4 = (int)((zero_end - (char*)cd) >> 4);
  zero_init<<<(zn4 + 255) / 256, 256, 0, stream>>>((int4*)cd, zn4);

  int eb = (E + 255) / 256;
  int nx4 = (N * IN_C) / 4;
  int conv_items = nx4 + 256 * 128 + 256 * 256;
  int cc_blocks = eb + (conv_items + 255) / 256;
  count_convert<<<cc_blocks, 256, 0, stream>>>(ei, ew, cd, wdeg, rank,
                                               src32, dst32, E,
                                               x, xbf, nx4, W1, w1hi, w1lo,
                                               W2, w2hi, w2lo);
  scan_dis<<<1, 1024, 0, stream>>>(cd, rowptr, dis, N);
  scatter_edges<<<eb, 256, 0, stream>>>(src32, dst32, ew, rowptr, rank, dis,
                                        col, coef, E);

  dim3 gg((N + 63) / 64, HID / 64);
  aggregate_pre<128><<<N, 256, 0, stream>>>(xbf, rowptr, col, coef, dis, axhi, axlo, N);
  gemm_mfma<<<gg, 256, 0, stream>>>(axhi, axlo, w1hi, w1lo, b1, hbf, N, IN_C);
  aggregate_pre<256><<<N, 256, 0, stream>>>(hbf, rowptr, col, coef, dis, ahhi, ahlo, N);
  gemm_mfma<<<gg, 256, 0, stream>>>(ahhi, ahlo, w2hi, w2lo, b2, hbf2, N, HID);

  pool_kernel<<<pool_blocks, 256, 0, stream>>>(hbf2, Wp, bp, wdeg, out, pp, N);
  edge_reduce<<<ER_BLOCKS, 256, 0, stream>>>(src32, dst32, ew, out, epart, E);
  finalize<<<1, 256, 0, stream>>>(epart, pp, pool_blocks, out, N, N * 16);
}